// Round 12
// baseline (3747.729 us; speedup 1.0000x reference)
//
#include <hip/hip_runtime.h>
#include <hip/hip_bf16.h>

typedef _Float16 h2_t  __attribute__((ext_vector_type(2)));
typedef _Float16 f16x8 __attribute__((ext_vector_type(8)));
typedef float    f32x4 __attribute__((ext_vector_type(4)));

#define NLG    196608
#define DIM    256
#define NRELS  237
#define BG     128
#define NN     256
#define MM     (BG*NN)      // 32768
#define G3     768          // 3*DIM
#define NSPLIT 64
#define NBWD   32           // backward blocks (4 graphs each: 2 groups x 2)
#define NFWD   64           // forward blocks (2 graphs each)
#define GRPSZ  29696        // per-group LDS region (29 KB)

// ---------------- A0: needed-relation flags ----------------
__global__ void k_needed(const int* __restrict__ rel, int* __restrict__ needed){
  int t = threadIdx.x;
  needed[t] = 0;
  __syncthreads();
  if (t < BG) atomicOr(&needed[rel[t]], 1);
}

// ---------------- B0: X16 = f16(relu(emds+bias)), h0 = max_n(node) ----------------
__global__ __launch_bounds__(256) void k_prep(const float* __restrict__ emds,
     const float* __restrict__ gbias, _Float16* __restrict__ X16, float* __restrict__ h0){
  int b = blockIdx.x, d = threadIdx.x;
  float bi = gbias[d];
  float mx = -3.4e38f;
  const float* src = emds + (size_t)b*NN*DIM + d;
  _Float16* dst = X16 + (size_t)b*NN*DIM + d;
  #pragma unroll 4
  for (int n = 0; n < NN; ++n){
    float v = src[(size_t)n*DIM];
    mx = fmaxf(mx, v);
    dst[(size_t)n*DIM] = (_Float16)fmaxf(v + bi, 0.f);
  }
  h0[b*DIM + d] = mx;
}

// ---------------- B2: wih_b, whh_b -> f16 row-major [768][256] ----------------
__global__ __launch_bounds__(256) void k_wconv(const float* __restrict__ wih,
      const float* __restrict__ whh, _Float16* __restrict__ wih16,
      _Float16* __restrict__ whh16){
  int t = blockIdx.x*256 + threadIdx.x;      // 0..49151
  const float* src; _Float16* dst; int i;
  if (t < 24576){ src = wih; dst = wih16; i = t*8; }
  else          { src = whh; dst = whh16; i = (t-24576)*8; }
  float4 a = *(const float4*)(src + i);
  float4 b = *(const float4*)(src + i + 4);
  f16x8 v;
  v[0]=(_Float16)a.x; v[1]=(_Float16)a.y; v[2]=(_Float16)a.z; v[3]=(_Float16)a.w;
  v[4]=(_Float16)b.x; v[5]=(_Float16)b.y; v[6]=(_Float16)b.z; v[7]=(_Float16)b.w;
  *(f16x8*)(dst + i) = v;
}

// ---------------- C: gi16[t][g][768] = f16(X @ w_ih_b^T + b_ih_b + bhh_fold) ----
__global__ __launch_bounds__(256) void k_gemm_gi(const _Float16* __restrict__ X16,
        const _Float16* __restrict__ wih16, const float* __restrict__ bih,
        const float* __restrict__ bhh, _Float16* __restrict__ gi16){
  __shared__ __align__(16) _Float16 Xs[64*136];
  __shared__ __align__(16) _Float16 Ws[64*136];
  int m0 = (blockIdx.x / 12) * 64;
  int n0 = (blockIdx.x % 12) * 64;
  int tix = threadIdx.x;
  int w = tix >> 6, l = tix & 63;
  int wm = (w & 1) * 32, wn = (w >> 1) * 32;
  int fr = l & 15, kg = l >> 4;
  f32x4 acc[2][2] = {};
  for (int kh = 0; kh < 2; ++kh){
    if (kh) __syncthreads();
    for (int rnd = 0; rnd < 4; ++rnd){
      int chunk = rnd*256 + tix;
      int r = chunk >> 4, cc = chunk & 15;
      *(f16x8*)&Xs[r*136 + cc*8] = *(const f16x8*)&X16[(size_t)(m0+r)*DIM + kh*128 + cc*8];
      *(f16x8*)&Ws[r*136 + cc*8] = *(const f16x8*)&wih16[(size_t)(n0+r)*DIM + kh*128 + cc*8];
    }
    __syncthreads();
    #pragma unroll
    for (int kk = 0; kk < 4; ++kk){
      int kcol = kk*32 + kg*8;
      f16x8 a0 = *(const f16x8*)&Xs[(wm + fr)*136 + kcol];
      f16x8 a1 = *(const f16x8*)&Xs[(wm + 16 + fr)*136 + kcol];
      f16x8 b0 = *(const f16x8*)&Ws[(wn + fr)*136 + kcol];
      f16x8 b1 = *(const f16x8*)&Ws[(wn + 16 + fr)*136 + kcol];
      acc[0][0] = __builtin_amdgcn_mfma_f32_16x16x32_f16(a0,b0,acc[0][0],0,0,0);
      acc[0][1] = __builtin_amdgcn_mfma_f32_16x16x32_f16(a0,b1,acc[0][1],0,0,0);
      acc[1][0] = __builtin_amdgcn_mfma_f32_16x16x32_f16(a1,b0,acc[1][0],0,0,0);
      acc[1][1] = __builtin_amdgcn_mfma_f32_16x16x32_f16(a1,b1,acc[1][1],0,0,0);
    }
  }
  int col0 = n0 + wn + fr;
  float bv0 = bih[col0] + (col0 < 512 ? bhh[col0] : 0.f);
  float bv1 = bih[col0+16] + (col0+16 < 512 ? bhh[col0+16] : 0.f);
  __syncthreads();
  _Float16* stage = (_Float16*)Xs;
  #pragma unroll
  for (int i = 0; i < 2; ++i)
  #pragma unroll
  for (int j = 0; j < 2; ++j){
    float bv = j ? bv1 : bv0;
    #pragma unroll
    for (int v = 0; v < 4; ++v){
      int srow = wm + i*16 + kg*4 + v;
      int scol = wn + j*16 + fr;
      stage[srow*72 + scol] = (_Float16)(acc[i][j][v] + bv);
    }
  }
  __syncthreads();
  {
    int r = tix >> 2, ch = tix & 3;
    int t0 = m0 & 255, gg = m0 >> 8;
    const f16x8* src = (const f16x8*)(stage + r*72 + ch*16);
    _Float16* dst = gi16 + (size_t)(t0 + r)*(BG*G3) + (size_t)gg*G3 + n0 + ch*16;
    *(f16x8*)(dst)   = src[0];
    *(f16x8*)(dst+8) = src[1];
  }
}

// ---- helpers ----
__device__ __forceinline__ float sigf(float x){
  return __builtin_amdgcn_rcpf(1.f + __expf(-x));
}
__device__ __forceinline__ float tanhff(float x){
  float e = __expf(2.f*x);
  return 1.f - 2.f*__builtin_amdgcn_rcpf(e + 1.f);
}

// ---------------- D: mega kernel (1024 threads) ----------------
// blocks 0..31: backward chains, TWO independent 8-wave groups per block
//   (2 graphs each -> 4 graphs/block). Groups share the s_barrier but have
//   independent LDS state -> 4 waves/SIMD with cross-group latency hiding.
// blocks 32..95: forward GRU (2 graphs per block, one per group).
// blocks 96..351: segment-sum partials (16 waves).
__global__ __launch_bounds__(1024) void k_mega(
    const _Float16* __restrict__ whh16, const _Float16* __restrict__ gi16,
    const float* __restrict__ h0, const float* __restrict__ bhh,
    float* __restrict__ bwd1, float* __restrict__ bwd0,
    const float* __restrict__ emds, const float* __restrict__ gbias,
    const float* __restrict__ wihf, const float* __restrict__ whhf,
    const float* __restrict__ bihf, const float* __restrict__ bhhf,
    float* __restrict__ fwd0, float* __restrict__ fwd1,
    const float* __restrict__ lgf, const int* __restrict__ lgt,
    const int* __restrict__ needed,
    float* __restrict__ part, int* __restrict__ cntp){
  __shared__ __align__(16) char smem[60416];   // 2*GRPSZ + 1KB bnl
  const int bid = blockIdx.x;
  const int tid = threadIdx.x;
  if (bid < NBWD){
    const int g  = tid >> 9;          // group 0/1
    const int t5 = tid & 511;         // id within group
    char* base = smem + g*GRPSZ;
    char* hls0 = base;                          // 8 KB h buffer A
    char* hls1 = base + 8192;                   // 8 KB h buffer B
    _Float16* gst0 = (_Float16*)(base + 16384); // 3 KB gi stage A
    _Float16* gst1 = (_Float16*)(base + 19456); // 3 KB gi stage B
    float* ghsf = (float*)(base + 22528);       // 6 KB gh stage [2][768]
    float* bnl  = (float*)(smem + 2*GRPSZ);     // 1 KB b_hh_n (shared)
    const int w = t5 >> 6, l = t5 & 63;
    const int lq = l >> 4, fr = l & 15;
    const int gq = fr & 1;                  // graph within group
    const int dt = (fr >> 3) & 1;           // row-half
    const int v  = (fr >> 1) & 3;           // component
    const int gg = bid*4 + g*2 + gq;
    const int d  = w*32 + dt*16 + lq*4 + v; // this lane's h dim
    const int dbase0 = w*32 + lq*4;
    const int hslot = ((d>>3)<<8) + (gq<<4) + ((d&7)<<1);
    const int goff = gq*G3 + d;

    // zero this group's h buffers (16 KB)
    for (int i = t5; i < 4096; i += 512) ((unsigned int*)base)[i] = 0u;
    if (tid < 256) bnl[tid] = bhh[512 + tid];
    __syncthreads();

    // ---- all 6 weight tiles in regs: wf[gate*2+dt][kc] (192 regs) ----
    f16x8 wf[6][8];
    #pragma unroll
    for (int t6 = 0; t6 < 6; ++t6){
      const int gate = t6 >> 1, dth = t6 & 1;
      const _Float16* wr = whh16 + (size_t)(gate*256 + w*32 + dth*16 + fr)*256 + lq*8;
      #pragma unroll
      for (int kc = 0; kc < 8; ++kc)
        wf[t6][kc] = *(const f16x8*)(wr + kc*32);
    }
    // ---- h_old (1 f32), write f16 into hls0 ----
    float hov = h0[(size_t)gg*DIM + d];
    *(_Float16*)(hls0 + hslot) = (_Float16)hov;
    // ---- gi stage prologue: t=255 chunk (2 graphs x 768 f16 = 3072 B) ----
    const char* gsrc = (const char*)gi16
        + ((size_t)255*BG + (size_t)(bid*4 + g*2))*(size_t)G3*2;
    if (t5 < 384){
      uint2 t0v = *(const uint2*)(gsrc + t5*8);
      *(uint2*)((char*)gst0 + t5*8) = t0v;
    }
    __syncthreads();

#define GRU_STEP(HR, HW, GR, GW, S)                                           \
    {                                                                         \
      uint2 greg;                                                             \
      if ((S) < 255){                                                         \
        gsrc -= (size_t)BG*G3*2;                                              \
        if (t5 < 384) greg = *(const uint2*)(gsrc + t5*8);                    \
      }                                                                       \
      float gr  = (float)((const _Float16*)(GR))[goff];                       \
      float gz  = (float)((const _Float16*)(GR))[goff+256];                   \
      float gnv = (float)((const _Float16*)(GR))[goff+512];                   \
      f32x4 acc0 = {}, acc1 = {}, acc2 = {}, acc3 = {};                       \
      f32x4 acc4 = *(const f32x4*)(bnl + dbase0);                             \
      f32x4 acc5 = *(const f32x4*)(bnl + dbase0 + 16);                        \
      __builtin_amdgcn_s_setprio(1);                                          \
      _Pragma("unroll")                                                       \
      for (int kc = 0; kc < 8; ++kc){                                         \
        f16x8 bf = *(const f16x8*)((HR) + kc*1024 + l*16);                    \
        acc0 = __builtin_amdgcn_mfma_f32_16x16x32_f16(wf[0][kc], bf, acc0,0,0,0);\
        acc1 = __builtin_amdgcn_mfma_f32_16x16x32_f16(wf[1][kc], bf, acc1,0,0,0);\
        acc2 = __builtin_amdgcn_mfma_f32_16x16x32_f16(wf[2][kc], bf, acc2,0,0,0);\
        acc3 = __builtin_amdgcn_mfma_f32_16x16x32_f16(wf[3][kc], bf, acc3,0,0,0);\
        acc4 = __builtin_amdgcn_mfma_f32_16x16x32_f16(wf[4][kc], bf, acc4,0,0,0);\
        acc5 = __builtin_amdgcn_mfma_f32_16x16x32_f16(wf[5][kc], bf, acc5,0,0,0);\
      }                                                                       \
      __builtin_amdgcn_s_setprio(0);                                          \
      /* gh stage: cols 0,1 only -> same-wave LDS roundtrip */                \
      if (fr < 2){                                                            \
        float* gb = ghsf + fr*768 + w*32 + lq*4;                              \
        *(f32x4*)(gb +   0) = acc0;                                           \
        *(f32x4*)(gb +  16) = acc1;                                           \
        *(f32x4*)(gb + 256) = acc2;                                           \
        *(f32x4*)(gb + 272) = acc3;                                           \
        *(f32x4*)(gb + 512) = acc4;                                           \
        *(f32x4*)(gb + 528) = acc5;                                           \
      }                                                                       \
      float ghr = ghsf[gq*768 + d];                                           \
      float ghz = ghsf[gq*768 + 256 + d];                                     \
      float ghn = ghsf[gq*768 + 512 + d];                                     \
      float r  = sigf(gr + ghr);                                              \
      float z  = sigf(gz + ghz);                                              \
      float nn = tanhff(gnv + r*ghn);                                         \
      float h  = z*(hov - nn) + nn;                                           \
      hov = h;                                                                \
      *(_Float16*)((HW) + hslot) = (_Float16)h;                               \
      if ((S) == 254) bwd1[(size_t)gg*DIM + d] = h;                           \
      if ((S) == 255) bwd0[(size_t)gg*DIM + d] = h;                           \
      if ((S) < 255 && t5 < 384)                                              \
        *(uint2*)((char*)(GW) + t5*8) = greg;                                 \
      asm volatile("s_waitcnt lgkmcnt(0)" ::: "memory");                      \
      __builtin_amdgcn_s_barrier();                                           \
    }

    for (int s2 = 0; s2 < 128; ++s2){
      GRU_STEP(hls0, hls1, gst0, gst1, 2*s2);
      GRU_STEP(hls1, hls0, gst1, gst0, 2*s2 + 1);
    }
#undef GRU_STEP
  } else if (bid < NBWD + NFWD){
    // ---- forward GRU: 2 graphs per block (one per 512-thread group) ----
    const int g = tid >> 9;
    const int j = tid & 511;
    const int b = (bid - NBWD)*2 + g;
    char* base = smem + g*8192;
    float* xv0  = (float*)base;
    float* xv1  = (float*)(base + 1024);
    float* hc   = (float*)(base + 2048);
    float* frz2 = (float*)(base + 3072);
    float* fhn2 = (float*)(base + 5120);
    float* fin2 = (float*)(base + 6144);
    if (j < 256){
      float bi = gbias[j];
      xv0[j] = fmaxf(emds[(size_t)b*NN*DIM + j] + bi, 0.f);
      xv1[j] = fmaxf(emds[(size_t)b*NN*DIM + DIM + j] + bi, 0.f);
      hc[j] = h0[(size_t)b*DIM + j];
    }
    __syncthreads();
    for (int st = 0; st < 2; ++st){
      const float* xv = st ? xv1 : xv0;
      const float4* wi = (const float4*)(wihf + (size_t)j*DIM);
      const float4* wh = (const float4*)(whhf + (size_t)j*DIM);
      const int row2 = 256 + j;
      const float4* wi2 = (const float4*)(wihf + (size_t)row2*DIM);
      const float4* wh2 = (const float4*)(whhf + (size_t)row2*DIM);
      float g1 = bihf[j] + bhhf[j];
      float gi2 = 0.f, gh2 = 0.f;
      if (j >= 256){ gi2 = bihf[row2]; gh2 = bhhf[row2]; }
      #pragma unroll 4
      for (int c = 0; c < 64; ++c){
        float4 x4 = *(const float4*)&xv[c*4];
        float4 h4 = *(const float4*)&hc[c*4];
        float4 a = wi[c], hh = wh[c];
        g1 += a.x*x4.x + a.y*x4.y + a.z*x4.z + a.w*x4.w;
        g1 += hh.x*h4.x + hh.y*h4.y + hh.z*h4.z + hh.w*h4.w;
        if (j >= 256){
          float4 a2 = wi2[c], hh2 = wh2[c];
          gi2 += a2.x*x4.x + a2.y*x4.y + a2.z*x4.z + a2.w*x4.w;
          gh2 += hh2.x*h4.x + hh2.y*h4.y + hh2.z*h4.z + hh2.w*h4.w;
        }
      }
      frz2[j] = g1;
      if (j >= 256){ fin2[j-256] = gi2; fhn2[j-256] = gh2; }
      __syncthreads();
      if (j < 256){
        float r = sigf(frz2[j]);
        float z = sigf(frz2[256+j]);
        float n = tanhff(fin2[j] + r*fhn2[j]);
        float hnew = z*(hc[j] - n) + n;
        hc[j] = hnew;
        if (st == 0) fwd0[(size_t)b*DIM + j] = hnew;
        else         fwd1[(size_t)b*DIM + j] = hnew;
      }
      __syncthreads();
    }
  } else {
    // ---- segment-sum partials: 64 splits x 4 dim-chunks, 1024 threads ----
    const int idx = bid - (NBWD + NFWD);
    const int split = idx >> 2, chunk = idx & 3;
    const int c0 = chunk * 64;
    float* acc  = (float*)smem;                 // NRELS*64*4 = 60672 ... fits? no
    // NOTE: 60672 > 60416-1920; use tighter layout: acc 60672 needs 60672
    // smem is 60416 -> shrink acc to use first 59392 + reuse: instead place
    // cacc/sneed AFTER 57344 boundary? acc must be NRELS*64*4=60672 B.
    // We give segsum the full smem by aliasing: acc occupies [0,60672) is
    // too big; instead process 2 chunks of 32 dims per block? Simpler:
    // use 59 KB acc for 236 rels and handle rel 236 separately via atomics?
    // -> choose: acc covers NRELS*64 floats but we only have 60416 B.
    // Use 60416-1024 for acc of 232 rels; remainder rels 232..236 go via
    // direct global atomics into part (rare rows). Implemented below.
    int*   cacc = (int*)(smem + 58368);         // 948 B
    int*   sneed= (int*)(smem + 59328);         // 948 B
    const int NACC = 228;                       // rels in LDS (228*256B=58368)
    const int t = tid, lane = t & 63, wv = t >> 6;
    for (int i = t; i < NACC*64; i += 1024) acc[i] = 0.f;
    for (int i = t; i < NRELS; i += 1024){ cacc[i] = 0; sneed[i] = needed[i]; }
    // zero the spill region of part for rels >= NACC handled by atomics:
    // (part was not pre-zeroed; do it for this split's high rels)
    for (int i = t; i < (NRELS-NACC)*64; i += 1024){
      int r = NACC + (i >> 6), dd = i & 63;
      part[((size_t)split*NRELS + r)*DIM + c0 + dd] = 0.f;
    }
    __syncthreads();
    const int RPS = NLG / NSPLIT;               // 3072
    const int rbase = split * RPS;
    for (int it = 0; it < RPS/32; ++it){        // 32 rows/iter (2 per wave)
      int r0 = rbase + it*32 + wv*2;
      int ty0 = lgt[r0], ty1 = lgt[r0+1];
      int nd0 = sneed[ty0], nd1 = sneed[ty1];
      float v0 = 0.f, v1 = 0.f;
      if (nd0) v0 = lgf[(size_t)r0*DIM + c0 + lane];
      if (nd1) v1 = lgf[(size_t)(r0+1)*DIM + c0 + lane];
      if (nd0){
        if (ty0 < NACC) atomicAdd(&acc[ty0*64 + lane], v0);
        else atomicAdd(&part[((size_t)split*NRELS + ty0)*DIM + c0 + lane], v0);
        if (chunk==0 && lane==0) atomicAdd(&cacc[ty0], 1);
      }
      if (nd1){
        if (ty1 < NACC) atomicAdd(&acc[ty1*64 + lane], v1);
        else atomicAdd(&part[((size_t)split*NRELS + ty1)*DIM + c0 + lane], v1);
        if (chunk==0 && lane==0) atomicAdd(&cacc[ty1], 1);
      }
    }
    __syncthreads();
    for (int i = t; i < NACC*64; i += 1024){
      int r = i >> 6, dd = i & 63;
      part[((size_t)split*NRELS + r)*DIM + c0 + dd] = acc[i];
    }
    if (chunk==0) for (int i = t; i < NRELS; i += 1024) cntp[split*NRELS + i] = cacc[i];
  }
}

// ---------------- E: head (computes its own relation mean from partials) ----
__global__ __launch_bounds__(256) void k_head(const float* __restrict__ fwd0,
     const float* __restrict__ fwd1, const float* __restrict__ bwd1,
     const float* __restrict__ bwd0,
     const float* __restrict__ part, const int* __restrict__ cntp,
     const int* __restrict__ rel,
     const float* __restrict__ W3, const float* __restrict__ b3,
     const float* __restrict__ W1, const float* __restrict__ b1,
     const float* __restrict__ W2, const float* __restrict__ b2,
     float* __restrict__ out){
  int b = blockIdx.x, d = threadIdx.x;
  __shared__ float cat0[512], cat1[512], feat[256];
  cat0[d] = fwd0[b*DIM+d]; cat0[256+d] = bwd0[b*DIM+d];
  cat1[d] = fwd1[b*DIM+d]; cat1[256+d] = bwd1[b*DIM+d];
  int lab = rel[b];
  float ps = 0.f;
  #pragma unroll 4
  for (int sp = 0; sp < NSPLIT; ++sp)
    ps += part[((size_t)sp*NRELS + lab)*DIM + d];
  int cs = 0;
  for (int sp = 0; sp < NSPLIT; ++sp) cs += cntp[sp*NRELS + lab];
  float mv = (cs > 0) ? ps / (float)cs : 0.f;
  __syncthreads();
  const float4* w3r = (const float4*)(W3 + (size_t)d*512);
  float hd = b3[d], td = b3[d];
  #pragma unroll 8
  for (int c = 0; c < 128; ++c){
    float4 w = w3r[c];
    hd += w.x*cat0[c*4] + w.y*cat0[c*4+1] + w.z*cat0[c*4+2] + w.w*cat0[c*4+3];
    td += w.x*cat1[c*4] + w.y*cat1[c*4+1] + w.z*cat1[c*4+2] + w.w*cat1[c*4+3];
  }
  feat[d] = fmaxf(hd, 0.f) + mv - fmaxf(td, 0.f);
  __syncthreads();
  const float4* w1r = (const float4*)(W1 + (size_t)d*DIM);
  float s = b1[d];
  #pragma unroll 8
  for (int c = 0; c < 64; ++c){
    float4 w = w1r[c];
    s += w.x*feat[c*4] + w.y*feat[c*4+1] + w.z*feat[c*4+2] + w.w*feat[c*4+3];
  }
  float v = W2[d] * s;
  #pragma unroll
  for (int o = 32; o > 0; o >>= 1) v += __shfl_down(v, o, 64);
  __shared__ float red[4];
  if ((d & 63) == 0) red[d >> 6] = v;
  __syncthreads();
  if (d == 0) out[b] = red[0] + red[1] + red[2] + red[3] + b2[0];
}

extern "C" void kernel_launch(void* const* d_in, const int* in_sizes, int n_in,
                              void* d_out, int out_size, void* d_ws, size_t ws_size,
                              hipStream_t stream){
  const float* lg_feats = (const float*)d_in[0];
  const int*   lg_type  = (const int*)d_in[1];
  const float* emds     = (const float*)d_in[2];
  const int*   rel      = (const int*)d_in[3];
  const float* gbias    = (const float*)d_in[4];
  const float* wihf     = (const float*)d_in[5];
  const float* whhf     = (const float*)d_in[6];
  const float* bihf     = (const float*)d_in[7];
  const float* bhhf     = (const float*)d_in[8];
  const float* wihb     = (const float*)d_in[9];
  const float* whhb     = (const float*)d_in[10];
  const float* bihb     = (const float*)d_in[11];
  const float* bhhb     = (const float*)d_in[12];
  const float* W3 = (const float*)d_in[13];
  const float* b3 = (const float*)d_in[14];
  const float* W1 = (const float*)d_in[15];
  const float* b1 = (const float*)d_in[16];
  const float* W2 = (const float*)d_in[17];
  const float* b2 = (const float*)d_in[18];
  float* out = (float*)d_out;

  char* ws = (char*)d_ws;
  size_t off = 0;
  auto alloc = [&](size_t bytes){ size_t o = off; off += (bytes + 255) & ~(size_t)255; return o; };
  size_t o_needed = alloc(256*4);
  size_t o_cntp   = alloc((size_t)NSPLIT*NRELS*4);
  size_t o_h0     = alloc((size_t)BG*DIM*4);
  size_t o_X16    = alloc((size_t)MM*DIM*2);
  size_t o_wih16  = alloc((size_t)G3*DIM*2);
  size_t o_whh16  = alloc((size_t)G3*DIM*2);
  size_t o_f0     = alloc((size_t)BG*DIM*4);
  size_t o_f1     = alloc((size_t)BG*DIM*4);
  size_t o_b1v    = alloc((size_t)BG*DIM*4);
  size_t o_b0v    = alloc((size_t)BG*DIM*4);
  size_t o_part   = alloc((size_t)NSPLIT*NRELS*DIM*4);
  size_t o_gi     = alloc((size_t)MM*G3*2);
  (void)ws_size; (void)in_sizes; (void)n_in; (void)out_size;

  int*       needed = (int*)(ws + o_needed);
  int*       cntp   = (int*)(ws + o_cntp);
  float*     h0     = (float*)(ws + o_h0);
  _Float16*  X16    = (_Float16*)(ws + o_X16);
  _Float16*  wih16  = (_Float16*)(ws + o_wih16);
  _Float16*  whh16  = (_Float16*)(ws + o_whh16);
  float*     f0     = (float*)(ws + o_f0);
  float*     f1     = (float*)(ws + o_f1);
  float*     b1v    = (float*)(ws + o_b1v);
  float*     b0v    = (float*)(ws + o_b0v);
  float*     part   = (float*)(ws + o_part);
  _Float16*  gi16   = (_Float16*)(ws + o_gi);

  k_needed<<<1, 256, 0, stream>>>(rel, needed);
  k_prep  <<<BG, 256, 0, stream>>>(emds, gbias, X16, h0);
  k_wconv <<<192, 256, 0, stream>>>(wihb, whhb, wih16, whh16);
  k_gemm_gi<<<(MM/64)*(G3/64), 256, 0, stream>>>(X16, wih16, bihb, bhhb, gi16);
  k_mega  <<<NBWD + NFWD + NSPLIT*4, 1024, 0, stream>>>(whh16, gi16, h0, bhhb,
                                       b1v, b0v,
                                       emds, gbias, wihf, whhf, bihf, bhhf, f0, f1,
                                       lg_feats, lg_type, needed, part, cntp);
  k_head  <<<BG, 256, 0, stream>>>(f0, f1, b1v, b0v, part, cntp, rel,
                                   W3, b3, W1, b1, W2, b2, out);
}

// Round 13
// 420.028 us; speedup vs baseline: 8.9226x; 8.9226x over previous
//
#include <hip/hip_runtime.h>
#include <hip/hip_bf16.h>

typedef _Float16 h2_t  __attribute__((ext_vector_type(2)));
typedef _Float16 f16x8 __attribute__((ext_vector_type(8)));
typedef float    f32x4 __attribute__((ext_vector_type(4)));

#define NLG    196608
#define DIM    256
#define NRELS  237
#define BG     128
#define NN     256
#define MM     (BG*NN)      // 32768
#define G3     768          // 3*DIM
#define NSPLIT 64
#define NBWD   64           // backward blocks (2 graphs each)

// ---------------- A0: needed-relation flags ----------------
__global__ void k_needed(const int* __restrict__ rel, int* __restrict__ needed){
  int t = threadIdx.x;
  needed[t] = 0;
  __syncthreads();
  if (t < BG) atomicOr(&needed[rel[t]], 1);
}

// ---------------- B0: X16 = f16(relu(emds+bias)), h0 = max_n(node) ----------------
__global__ __launch_bounds__(256) void k_prep(const float* __restrict__ emds,
     const float* __restrict__ gbias, _Float16* __restrict__ X16, float* __restrict__ h0){
  int b = blockIdx.x, d = threadIdx.x;
  float bi = gbias[d];
  float mx = -3.4e38f;
  const float* src = emds + (size_t)b*NN*DIM + d;
  _Float16* dst = X16 + (size_t)b*NN*DIM + d;
  #pragma unroll 4
  for (int n = 0; n < NN; ++n){
    float v = src[(size_t)n*DIM];
    mx = fmaxf(mx, v);
    dst[(size_t)n*DIM] = (_Float16)fmaxf(v + bi, 0.f);
  }
  h0[b*DIM + d] = mx;
}

// ---------------- B2: wih_b, whh_b -> f16 row-major [768][256] ----------------
__global__ __launch_bounds__(256) void k_wconv(const float* __restrict__ wih,
      const float* __restrict__ whh, _Float16* __restrict__ wih16,
      _Float16* __restrict__ whh16){
  int t = blockIdx.x*256 + threadIdx.x;      // 0..49151
  const float* src; _Float16* dst; int i;
  if (t < 24576){ src = wih; dst = wih16; i = t*8; }
  else          { src = whh; dst = whh16; i = (t-24576)*8; }
  float4 a = *(const float4*)(src + i);
  float4 b = *(const float4*)(src + i + 4);
  f16x8 v;
  v[0]=(_Float16)a.x; v[1]=(_Float16)a.y; v[2]=(_Float16)a.z; v[3]=(_Float16)a.w;
  v[4]=(_Float16)b.x; v[5]=(_Float16)b.y; v[6]=(_Float16)b.z; v[7]=(_Float16)b.w;
  *(f16x8*)(dst + i) = v;
}

// ---------------- C: gi16[t][g][768] = f16(X @ w_ih_b^T + b_ih_b + bhh_fold) ----
__global__ __launch_bounds__(256) void k_gemm_gi(const _Float16* __restrict__ X16,
        const _Float16* __restrict__ wih16, const float* __restrict__ bih,
        const float* __restrict__ bhh, _Float16* __restrict__ gi16){
  __shared__ __align__(16) _Float16 Xs[64*136];
  __shared__ __align__(16) _Float16 Ws[64*136];
  int m0 = (blockIdx.x / 12) * 64;
  int n0 = (blockIdx.x % 12) * 64;
  int tix = threadIdx.x;
  int w = tix >> 6, l = tix & 63;
  int wm = (w & 1) * 32, wn = (w >> 1) * 32;
  int fr = l & 15, kg = l >> 4;
  f32x4 acc[2][2] = {};
  for (int kh = 0; kh < 2; ++kh){
    if (kh) __syncthreads();
    for (int rnd = 0; rnd < 4; ++rnd){
      int chunk = rnd*256 + tix;
      int r = chunk >> 4, cc = chunk & 15;
      *(f16x8*)&Xs[r*136 + cc*8] = *(const f16x8*)&X16[(size_t)(m0+r)*DIM + kh*128 + cc*8];
      *(f16x8*)&Ws[r*136 + cc*8] = *(const f16x8*)&wih16[(size_t)(n0+r)*DIM + kh*128 + cc*8];
    }
    __syncthreads();
    #pragma unroll
    for (int kk = 0; kk < 4; ++kk){
      int kcol = kk*32 + kg*8;
      f16x8 a0 = *(const f16x8*)&Xs[(wm + fr)*136 + kcol];
      f16x8 a1 = *(const f16x8*)&Xs[(wm + 16 + fr)*136 + kcol];
      f16x8 b0 = *(const f16x8*)&Ws[(wn + fr)*136 + kcol];
      f16x8 b1 = *(const f16x8*)&Ws[(wn + 16 + fr)*136 + kcol];
      acc[0][0] = __builtin_amdgcn_mfma_f32_16x16x32_f16(a0,b0,acc[0][0],0,0,0);
      acc[0][1] = __builtin_amdgcn_mfma_f32_16x16x32_f16(a0,b1,acc[0][1],0,0,0);
      acc[1][0] = __builtin_amdgcn_mfma_f32_16x16x32_f16(a1,b0,acc[1][0],0,0,0);
      acc[1][1] = __builtin_amdgcn_mfma_f32_16x16x32_f16(a1,b1,acc[1][1],0,0,0);
    }
  }
  int col0 = n0 + wn + fr;
  float bv0 = bih[col0] + (col0 < 512 ? bhh[col0] : 0.f);
  float bv1 = bih[col0+16] + (col0+16 < 512 ? bhh[col0+16] : 0.f);
  __syncthreads();
  _Float16* stage = (_Float16*)Xs;
  #pragma unroll
  for (int i = 0; i < 2; ++i)
  #pragma unroll
  for (int j = 0; j < 2; ++j){
    float bv = j ? bv1 : bv0;
    #pragma unroll
    for (int v = 0; v < 4; ++v){
      int srow = wm + i*16 + kg*4 + v;
      int scol = wn + j*16 + fr;
      stage[srow*72 + scol] = (_Float16)(acc[i][j][v] + bv);
    }
  }
  __syncthreads();
  {
    int r = tix >> 2, ch = tix & 3;
    int t0 = m0 & 255, gg = m0 >> 8;
    const f16x8* src = (const f16x8*)(stage + r*72 + ch*16);
    _Float16* dst = gi16 + (size_t)(t0 + r)*(BG*G3) + (size_t)gg*G3 + n0 + ch*16;
    *(f16x8*)(dst)   = src[0];
    *(f16x8*)(dst+8) = src[1];
  }
}

// ---- helpers ----
__device__ __forceinline__ float sigf(float x){
  return __builtin_amdgcn_rcpf(1.f + __expf(-x));
}
__device__ __forceinline__ float tanhff(float x){
  float e = __expf(2.f*x);
  return 1.f - 2.f*__builtin_amdgcn_rcpf(e + 1.f);
}

// ---------------- D: mega kernel ----------------
// blocks 0..63: backward chains, 2 graphs each. All 6 W tiles in regs;
//   DEPTH-2 gi prefetch: data written to LDS one full step after its load
//   was issued (no vmcnt stall at the write), next load has 2 steps cover.
// blocks 64..191: forward GRU (2 steps).
// blocks 192..447: segment-sum partials.
__global__ __launch_bounds__(512, 2) void k_mega(
    const _Float16* __restrict__ whh16, const _Float16* __restrict__ gi16,
    const float* __restrict__ h0, const float* __restrict__ bhh,
    float* __restrict__ bwd1, float* __restrict__ bwd0,
    const float* __restrict__ emds, const float* __restrict__ gbias,
    const float* __restrict__ wihf, const float* __restrict__ whhf,
    const float* __restrict__ bihf, const float* __restrict__ bhhf,
    float* __restrict__ fwd0, float* __restrict__ fwd1,
    const float* __restrict__ lgf, const int* __restrict__ lgt,
    const int* __restrict__ needed,
    float* __restrict__ part, int* __restrict__ cntp){
  __shared__ __align__(16) char smem[63488];
  const int bid = blockIdx.x;
  if (bid < NBWD){
    char* hls0 = smem;                          // 8 KB h buffer A
    char* hls1 = smem + 8192;                   // 8 KB h buffer B
    float* bnl = (float*)(smem + 16384);        // 1 KB b_hh_n
    _Float16* gst0 = (_Float16*)(smem + 17408); // 3 KB gi stage A
    _Float16* gst1 = (_Float16*)(smem + 20480); // 3 KB gi stage B
    float* ghsf = (float*)(smem + 23552);       // 6 KB gh stage [2][768]
    const int tid = threadIdx.x;
    const int w = tid >> 6, l = tid & 63;
    const int lq = l >> 4, fr = l & 15;
    const int gq = fr & 1;                  // graph within block
    const int dt = (fr >> 3) & 1;           // row-half
    const int v  = (fr >> 1) & 3;           // component
    const int gg = bid*2 + gq;
    const int d  = w*32 + dt*16 + lq*4 + v; // this lane's h dim
    const int dbase0 = w*32 + lq*4;         // acc bias row base (dt=0)
    const int hslot = ((d>>3)<<8) + (gq<<4) + ((d&7)<<1);
    const int goff = gq*G3 + d;             // gi stage read offset (f16 idx)

    // zero both h buffers (16 KB) so cols 2..15 stay 0 forever
    for (int i = tid; i < 4096; i += 512) ((unsigned int*)smem)[i] = 0u;
    if (tid < 256) bnl[tid] = bhh[512 + tid];
    __syncthreads();

    // ---- all 6 weight tiles in regs: wf[gate*2+dt][kc] (192 regs) ----
    f16x8 wf[6][8];
    #pragma unroll
    for (int t6 = 0; t6 < 6; ++t6){
      const int gate = t6 >> 1, dth = t6 & 1;
      const _Float16* wr = whh16 + (size_t)(gate*256 + w*32 + dth*16 + fr)*256 + lq*8;
      #pragma unroll
      for (int kc = 0; kc < 8; ++kc)
        wf[t6][kc] = *(const f16x8*)(wr + kc*32);
    }
    // ---- h_old (1 f32), write f16 into hls0 ----
    float hov = h0[(size_t)gg*DIM + d];
    *(_Float16*)(hls0 + hslot) = (_Float16)hov;
    // ---- gi prologue: stage S=0 (t=255) into gst0; preload S=1 into greg ----
    const char* gsrc = (const char*)gi16 + ((size_t)255*BG + (size_t)bid*2)*(size_t)G3*2;
    if (tid < 384){
      uint2 t0v = *(const uint2*)(gsrc + tid*8);
      *(uint2*)((char*)gst0 + tid*8) = t0v;
    }
    gsrc -= (size_t)BG*G3*2;
    uint2 greg = {0u, 0u};
    if (tid < 384) greg = *(const uint2*)(gsrc + tid*8);   // data for S=1
    __syncthreads();

#define GRU_STEP(HR, HW, GR, GW, S)                                           \
    {                                                                         \
      /* write gi data for step S+1 (loaded at step S-1: no vmcnt stall) */   \
      if ((S) < 255 && tid < 384)                                             \
        *(uint2*)((char*)(GW) + tid*8) = greg;                                \
      /* issue load for step S+2 (2 full steps of latency cover) */           \
      if ((S) < 254){                                                         \
        gsrc -= (size_t)BG*G3*2;                                              \
        if (tid < 384) greg = *(const uint2*)(gsrc + tid*8);                  \
      }                                                                       \
      float gr  = (float)((const _Float16*)(GR))[goff];                       \
      float gz  = (float)((const _Float16*)(GR))[goff+256];                   \
      float gnv = (float)((const _Float16*)(GR))[goff+512];                   \
      f32x4 acc0 = {}, acc1 = {}, acc2 = {}, acc3 = {};                       \
      f32x4 acc4 = *(const f32x4*)(bnl + dbase0);                             \
      f32x4 acc5 = *(const f32x4*)(bnl + dbase0 + 16);                        \
      _Pragma("unroll")                                                       \
      for (int kc = 0; kc < 8; ++kc){                                         \
        f16x8 bf = *(const f16x8*)((HR) + kc*1024 + l*16);                    \
        acc0 = __builtin_amdgcn_mfma_f32_16x16x32_f16(wf[0][kc], bf, acc0,0,0,0);\
        acc1 = __builtin_amdgcn_mfma_f32_16x16x32_f16(wf[1][kc], bf, acc1,0,0,0);\
        acc2 = __builtin_amdgcn_mfma_f32_16x16x32_f16(wf[2][kc], bf, acc2,0,0,0);\
        acc3 = __builtin_amdgcn_mfma_f32_16x16x32_f16(wf[3][kc], bf, acc3,0,0,0);\
        acc4 = __builtin_amdgcn_mfma_f32_16x16x32_f16(wf[4][kc], bf, acc4,0,0,0);\
        acc5 = __builtin_amdgcn_mfma_f32_16x16x32_f16(wf[5][kc], bf, acc5,0,0,0);\
      }                                                                       \
      /* gh stage: cols 0,1 only -> same-wave LDS roundtrip */                \
      if (fr < 2){                                                            \
        float* gb = ghsf + fr*768 + w*32 + lq*4;                              \
        *(f32x4*)(gb +   0) = acc0;                                           \
        *(f32x4*)(gb +  16) = acc1;                                           \
        *(f32x4*)(gb + 256) = acc2;                                           \
        *(f32x4*)(gb + 272) = acc3;                                           \
        *(f32x4*)(gb + 512) = acc4;                                           \
        *(f32x4*)(gb + 528) = acc5;                                           \
      }                                                                       \
      float ghr = ghsf[gq*768 + d];                                           \
      float ghz = ghsf[gq*768 + 256 + d];                                     \
      float ghn = ghsf[gq*768 + 512 + d];                                     \
      float r  = sigf(gr + ghr);                                              \
      float z  = sigf(gz + ghz);                                              \
      float nn = tanhff(gnv + r*ghn);                                         \
      float h  = z*(hov - nn) + nn;                                           \
      hov = h;                                                                \
      *(_Float16*)((HW) + hslot) = (_Float16)h;                               \
      if ((S) == 254) bwd1[(size_t)gg*DIM + d] = h;                           \
      if ((S) == 255) bwd0[(size_t)gg*DIM + d] = h;                           \
      asm volatile("s_waitcnt lgkmcnt(0)" ::: "memory");                      \
      __builtin_amdgcn_s_barrier();                                           \
    }

    for (int s2 = 0; s2 < 128; ++s2){
      GRU_STEP(hls0, hls1, gst0, gst1, 2*s2);
      GRU_STEP(hls1, hls0, gst1, gst0, 2*s2 + 1);
    }
#undef GRU_STEP
  } else if (bid < NBWD + BG){
    // ---- forward GRU: fwd[0], fwd[1] only ----
    const int b = bid - NBWD;
    float* xv0  = (float*)smem;
    float* xv1  = (float*)(smem + 1024);
    float* hc   = (float*)(smem + 2048);
    float* frz2 = (float*)(smem + 3072);
    float* fhn2 = (float*)(smem + 5120);
    float* fin2 = (float*)(smem + 6144);
    const int j = threadIdx.x;
    if (j < 256){
      float bi = gbias[j];
      xv0[j] = fmaxf(emds[(size_t)b*NN*DIM + j] + bi, 0.f);
      xv1[j] = fmaxf(emds[(size_t)b*NN*DIM + DIM + j] + bi, 0.f);
      hc[j] = h0[(size_t)b*DIM + j];
    }
    __syncthreads();
    for (int st = 0; st < 2; ++st){
      const float* xv = st ? xv1 : xv0;
      const float4* wi = (const float4*)(wihf + (size_t)j*DIM);
      const float4* wh = (const float4*)(whhf + (size_t)j*DIM);
      const int row2 = 256 + j;
      const float4* wi2 = (const float4*)(wihf + (size_t)row2*DIM);
      const float4* wh2 = (const float4*)(whhf + (size_t)row2*DIM);
      float g1 = bihf[j] + bhhf[j];
      float gi2 = 0.f, gh2 = 0.f;
      if (j >= 256){ gi2 = bihf[row2]; gh2 = bhhf[row2]; }
      #pragma unroll 4
      for (int c = 0; c < 64; ++c){
        float4 x4 = *(const float4*)&xv[c*4];
        float4 h4 = *(const float4*)&hc[c*4];
        float4 a = wi[c], hh = wh[c];
        g1 += a.x*x4.x + a.y*x4.y + a.z*x4.z + a.w*x4.w;
        g1 += hh.x*h4.x + hh.y*h4.y + hh.z*h4.z + hh.w*h4.w;
        if (j >= 256){
          float4 a2 = wi2[c], hh2 = wh2[c];
          gi2 += a2.x*x4.x + a2.y*x4.y + a2.z*x4.z + a2.w*x4.w;
          gh2 += hh2.x*h4.x + hh2.y*h4.y + hh2.z*h4.z + hh2.w*h4.w;
        }
      }
      frz2[j] = g1;
      if (j >= 256){ fin2[j-256] = gi2; fhn2[j-256] = gh2; }
      __syncthreads();
      if (j < 256){
        float r = sigf(frz2[j]);
        float z = sigf(frz2[256+j]);
        float n = tanhff(fin2[j] + r*fhn2[j]);
        float hnew = z*(hc[j] - n) + n;
        hc[j] = hnew;
        if (st == 0) fwd0[(size_t)b*DIM + j] = hnew;
        else         fwd1[(size_t)b*DIM + j] = hnew;
      }
      __syncthreads();
    }
  } else {
    // ---- segment-sum partials: 64 splits x 4 dim-chunks, 512 threads ----
    const int idx = bid - (NBWD + BG);
    const int split = idx >> 2, chunk = idx & 3;
    const int c0 = chunk * 64;
    float* acc  = (float*)smem;                 // NRELS*64*4 = 60672
    int*   cacc = (int*)(smem + 60672);
    int*   sneed= (int*)(smem + 61632);
    const int t = threadIdx.x, lane = t & 63, wv = t >> 6;
    for (int i = t; i < NRELS*64; i += 512) acc[i] = 0.f;
    for (int i = t; i < NRELS; i += 512){ cacc[i] = 0; sneed[i] = needed[i]; }
    __syncthreads();
    const int RPS = NLG / NSPLIT;               // 3072
    const int rbase = split * RPS;
    for (int it = 0; it < RPS/16; ++it){
      int r0 = rbase + it*16 + wv*2;
      int ty0 = lgt[r0], ty1 = lgt[r0+1];
      int nd0 = sneed[ty0], nd1 = sneed[ty1];
      float v0 = 0.f, v1 = 0.f;
      if (nd0) v0 = lgf[(size_t)r0*DIM + c0 + lane];
      if (nd1) v1 = lgf[(size_t)(r0+1)*DIM + c0 + lane];
      if (nd0){ atomicAdd(&acc[ty0*64 + lane], v0);
                if (chunk==0 && lane==0) atomicAdd(&cacc[ty0], 1); }
      if (nd1){ atomicAdd(&acc[ty1*64 + lane], v1);
                if (chunk==0 && lane==0) atomicAdd(&cacc[ty1], 1); }
    }
    __syncthreads();
    for (int i = t; i < NRELS*64; i += 512){
      int r = i >> 6, dd = i & 63;
      part[((size_t)split*NRELS + r)*DIM + c0 + dd] = acc[i];
    }
    if (chunk==0) for (int i = t; i < NRELS; i += 512) cntp[split*NRELS + i] = cacc[i];
  }
}

// ---------------- E: head (computes its own relation mean from partials) ----
__global__ __launch_bounds__(256) void k_head(const float* __restrict__ fwd0,
     const float* __restrict__ fwd1, const float* __restrict__ bwd1,
     const float* __restrict__ bwd0,
     const float* __restrict__ part, const int* __restrict__ cntp,
     const int* __restrict__ rel,
     const float* __restrict__ W3, const float* __restrict__ b3,
     const float* __restrict__ W1, const float* __restrict__ b1,
     const float* __restrict__ W2, const float* __restrict__ b2,
     float* __restrict__ out){
  int b = blockIdx.x, d = threadIdx.x;
  __shared__ float cat0[512], cat1[512], feat[256];
  cat0[d] = fwd0[b*DIM+d]; cat0[256+d] = bwd0[b*DIM+d];
  cat1[d] = fwd1[b*DIM+d]; cat1[256+d] = bwd1[b*DIM+d];
  int lab = rel[b];
  float ps = 0.f;
  #pragma unroll 4
  for (int sp = 0; sp < NSPLIT; ++sp)
    ps += part[((size_t)sp*NRELS + lab)*DIM + d];
  int cs = 0;
  for (int sp = 0; sp < NSPLIT; ++sp) cs += cntp[sp*NRELS + lab];
  float mv = (cs > 0) ? ps / (float)cs : 0.f;
  __syncthreads();
  const float4* w3r = (const float4*)(W3 + (size_t)d*512);
  float hd = b3[d], td = b3[d];
  #pragma unroll 8
  for (int c = 0; c < 128; ++c){
    float4 w = w3r[c];
    hd += w.x*cat0[c*4] + w.y*cat0[c*4+1] + w.z*cat0[c*4+2] + w.w*cat0[c*4+3];
    td += w.x*cat1[c*4] + w.y*cat1[c*4+1] + w.z*cat1[c*4+2] + w.w*cat1[c*4+3];
  }
  feat[d] = fmaxf(hd, 0.f) + mv - fmaxf(td, 0.f);
  __syncthreads();
  const float4* w1r = (const float4*)(W1 + (size_t)d*DIM);
  float s = b1[d];
  #pragma unroll 8
  for (int c = 0; c < 64; ++c){
    float4 w = w1r[c];
    s += w.x*feat[c*4] + w.y*feat[c*4+1] + w.z*feat[c*4+2] + w.w*feat[c*4+3];
  }
  float v = W2[d] * s;
  #pragma unroll
  for (int o = 32; o > 0; o >>= 1) v += __shfl_down(v, o, 64);
  __shared__ float red[4];
  if ((d & 63) == 0) red[d >> 6] = v;
  __syncthreads();
  if (d == 0) out[b] = red[0] + red[1] + red[2] + red[3] + b2[0];
}

extern "C" void kernel_launch(void* const* d_in, const int* in_sizes, int n_in,
                              void* d_out, int out_size, void* d_ws, size_t ws_size,
                              hipStream_t stream){
  const float* lg_feats = (const float*)d_in[0];
  const int*   lg_type  = (const int*)d_in[1];
  const float* emds     = (const float*)d_in[2];
  const int*   rel      = (const int*)d_in[3];
  const float* gbias    = (const float*)d_in[4];
  const float* wihf     = (const float*)d_in[5];
  const float* whhf     = (const float*)d_in[6];
  const float* bihf     = (const float*)d_in[7];
  const float* bhhf     = (const float*)d_in[8];
  const float* wihb     = (const float*)d_in[9];
  const float* whhb     = (const float*)d_in[10];
  const float* bihb     = (const float*)d_in[11];
  const float* bhhb     = (const float*)d_in[12];
  const float* W3 = (const float*)d_in[13];
  const float* b3 = (const float*)d_in[14];
  const float* W1 = (const float*)d_in[15];
  const float* b1 = (const float*)d_in[16];
  const float* W2 = (const float*)d_in[17];
  const float* b2 = (const float*)d_in[18];
  float* out = (float*)d_out;

  char* ws = (char*)d_ws;
  size_t off = 0;
  auto alloc = [&](size_t bytes){ size_t o = off; off += (bytes + 255) & ~(size_t)255; return o; };
  size_t o_needed = alloc(256*4);
  size_t o_cntp   = alloc((size_t)NSPLIT*NRELS*4);
  size_t o_h0     = alloc((size_t)BG*DIM*4);
  size_t o_X16    = alloc((size_t)MM*DIM*2);
  size_t o_wih16  = alloc((size_t)G3*DIM*2);
  size_t o_whh16  = alloc((size_t)G3*DIM*2);
  size_t o_f0     = alloc((size_t)BG*DIM*4);
  size_t o_f1     = alloc((size_t)BG*DIM*4);
  size_t o_b1v    = alloc((size_t)BG*DIM*4);
  size_t o_b0v    = alloc((size_t)BG*DIM*4);
  size_t o_part   = alloc((size_t)NSPLIT*NRELS*DIM*4);
  size_t o_gi     = alloc((size_t)MM*G3*2);
  (void)ws_size; (void)in_sizes; (void)n_in; (void)out_size;

  int*       needed = (int*)(ws + o_needed);
  int*       cntp   = (int*)(ws + o_cntp);
  float*     h0     = (float*)(ws + o_h0);
  _Float16*  X16    = (_Float16*)(ws + o_X16);
  _Float16*  wih16  = (_Float16*)(ws + o_wih16);
  _Float16*  whh16  = (_Float16*)(ws + o_whh16);
  float*     f0     = (float*)(ws + o_f0);
  float*     f1     = (float*)(ws + o_f1);
  float*     b1v    = (float*)(ws + o_b1v);
  float*     b0v    = (float*)(ws + o_b0v);
  float*     part   = (float*)(ws + o_part);
  _Float16*  gi16   = (_Float16*)(ws + o_gi);

  k_needed<<<1, 256, 0, stream>>>(rel, needed);
  k_prep  <<<BG, 256, 0, stream>>>(emds, gbias, X16, h0);
  k_wconv <<<192, 256, 0, stream>>>(wihb, whhb, wih16, whh16);
  k_gemm_gi<<<(MM/64)*(G3/64), 256, 0, stream>>>(X16, wih16, bihb, bhhb, gi16);
  k_mega  <<<NBWD + BG + NSPLIT*4, 512, 0, stream>>>(whh16, gi16, h0, bhhb, b1v, b0v,
                                       emds, gbias, wihf, whhf, bihf, bhhf, f0, f1,
                                       lg_feats, lg_type, needed, part, cntp);
  k_head  <<<BG, 256, 0, stream>>>(f0, f1, b1v, b0v, part, cntp, rel,
                                   W3, b3, W1, b1, W2, b2, out);
}